// Round 5
// baseline (128.255 us; speedup 1.0000x reference)
//
#include <hip/hip_runtime.h>
#include <math.h>

#define N 384
#define EPSA 1e-5f   // drop A below this; dropped triplet terms < ~5e-8 each
                     // (triangle inequality: A_ij<eps => D_ij>4.8 => A_jk*A_ik < 3e-3)

__device__ __forceinline__ float wave_reduce(float v) {
#pragma unroll
    for (int o = 32; o > 0; o >>= 1) v += __shfl_down(v, o, 64);
    return v;
}

// ---------------- Kernel 1: pairs + sorted neighbor compaction ----------------
// block per atom i (128 thr): dense A row (for gathers), rad[i], ang[i]=0,
// and a SORTED compact neighbor list: nbr4[slot]=(ux,uy,uz,A_ij), nbrJ[slot]=j.
__global__ __launch_bounds__(128) void pair_kernel(
    const float* __restrict__ x, float* __restrict__ A,
    float4* __restrict__ nbr4, int* __restrict__ nbrJ, int* __restrict__ cnt,
    float* __restrict__ rad, float* __restrict__ ang) {
    const int i = blockIdx.x;
    const int t = threadIdx.x;
    const int lane = t & 63, w = t >> 6;
    const float xi0 = x[3 * i + 0], xi1 = x[3 * i + 1], xi2 = x[3 * i + 2];

    float racc = 0.0f;
    float4 val[3];
    int keep[3];
#pragma unroll
    for (int r = 0; r < 3; ++r) {
        const int j = t + 128 * r;
        float dx = xi0 - x[3 * j + 0];
        float dy = xi1 - x[3 * j + 1];
        float dz = xi2 - x[3 * j + 2];
        float d2 = dx * dx + dy * dy + dz * dz;
        float a = 0.0f, rr = 0.0f, inv = 0.0f;
        if (j != i) {
            float d = sqrtf(d2);
            if (d <= 6.0f) {
                float fc = 0.5f * (__cosf(0.52359877559829887f * d) + 1.0f);
                a = __expf(-0.5f * d2) * fc;
                float dm = d - 1.0f;  // RS = 1
                rr = __expf(-0.5f * dm * dm) * fc;
            }
            inv = rsqrtf(d2);
        }
        A[i * N + j] = a;
        racc += rr;
        val[r] = make_float4(dx * inv, dy * inv, dz * inv, a);
        keep[r] = (a > EPSA) ? 1 : 0;
    }

    // sorted compaction: chunk c = (j>>6) = w + 2r; ballot + prefix per chunk
    __shared__ int bcnt[6], bbase[6];
    int pfx[3];
#pragma unroll
    for (int r = 0; r < 3; ++r) {
        unsigned long long m = __ballot(keep[r]);
        pfx[r] = __popcll(m & ((1ull << lane) - 1ull));
        if (lane == 0) bcnt[w + 2 * r] = __popcll(m);
    }
    __syncthreads();
    if (t == 0) {
        int s = 0;
#pragma unroll
        for (int c = 0; c < 6; ++c) { bbase[c] = s; s += bcnt[c]; }
        cnt[i] = s;
        ang[i] = 0.0f;
    }
    __syncthreads();
#pragma unroll
    for (int r = 0; r < 3; ++r) {
        if (keep[r]) {
            const int slot = bbase[w + 2 * r] + pfx[r];
            nbr4[i * N + slot] = val[r];
            nbrJ[i * N + slot] = t + 128 * r;
        }
    }

    __shared__ float red[2];
    float v = wave_reduce(racc);
    if (lane == 0) red[w] = v;
    __syncthreads();
    if (t == 0) rad[i] = red[0] + red[1];
}

// ---------------- Kernel 2: angular sum over compact rectangle ----------------
// grid (N, 8): y = kc*4 + jc. kc in {0,1} (256-wide k chunks; kc=1 exits unless
// n>256, ~0.1% of atoms). jc splits the j range in 4 for occupancy. 256 threads,
// 1 compact-k per thread (u_k pre-scaled by -lambda, A_ik in registers).
// Full rectangle over compact list = 2x the triangle; 0.5 folded into mlp's g0.
__global__ __launch_bounds__(256) void ang_kernel(
    const float* __restrict__ A, const float4* __restrict__ nbr4,
    const int* __restrict__ nbrJ, const int* __restrict__ cnt,
    float* __restrict__ ang) {
    const int i = blockIdx.x;
    const int kc = blockIdx.y >> 2;
    const int jc = blockIdx.y & 3;
    const int t = threadIdx.x;
    const int n = cnt[i];
    if (kc * 256 >= n) return;

    const int qn = (n + 3) >> 2;           // j per jc block (<= 96)
    const int js = jc * qn;
    const int je = min(js + qn, n);
    if (js >= je) return;

    __shared__ float4 sh4[96];
    __shared__ int shJ[96];
    for (int s = js + t; s < je; s += 256) {
        sh4[s - js] = nbr4[i * N + s];
        shJ[s - js] = nbrJ[i * N + s];
    }

    const int ks = kc * 256 + t;
    const int valid = ks < n;
    float4 K = valid ? nbr4[i * N + ks] : make_float4(0.f, 0.f, 0.f, 0.f);
    const int kcol = valid ? nbrJ[i * N + ks] : 0;
    // fold -lambda: base = 1 + 0.8*cos = 1 + u_j . (-0.8*u_k)
    const float kx = -0.8f * K.x, ky = -0.8f * K.y, kz = -0.8f * K.z, kA = K.w;
    __syncthreads();

    float acc = 0.0f;
    int jo = __builtin_amdgcn_readfirstlane(shJ[0]);
    float a = A[jo * N + kcol];            // A_jk gather, sorted kcol => ~7 lines
    for (int s = js; s < je; ++s) {
        float an = 0.0f;
        if (s + 1 < je) {                  // software-pipelined prefetch
            int jn = __builtin_amdgcn_readfirstlane(shJ[s - js + 1]);
            an = A[jn * N + kcol];
        }
        float4 J = sh4[s - js];            // broadcast (conflict-free)
        float b = fmaxf(fmaf(J.x, kx, fmaf(J.y, ky, fmaf(J.z, kz, 1.0f))), 1e-6f);
        float p = __expf(0.6f * __logf(b));   // base^zeta
        acc = fmaf(J.w * a, p, acc);
        a = an;
    }
    acc *= kA;

    __shared__ float red[4];
    float v = wave_reduce(acc);
    if ((t & 63) == 0) red[t >> 6] = v;
    __syncthreads();
    if (t == 0) atomicAdd(&ang[i], red[0] + red[1] + red[2] + red[3]);
}

// ---------------- Kernel 3: MLPs + select ----------------
// 24 blocks x 64 threads; t = local*4 + net*2 + half; halves split the 40-row
// hidden-2 loop, combined via shfl. Per-net LDS stride 1804 floats:
//   w1[80]@0  b1[40]@80  w2[1600]@120  b2[40]@1720  w3[40]@1760  b3[1]@1800
#define WSTRIDE 1804
__global__ __launch_bounds__(64) void mlp_kernel(
    const float* __restrict__ ang, const float* __restrict__ rad,
    float* __restrict__ out,
    const float* w1a, const float* b1a, const float* w2a, const float* b2a,
    const float* w3a, const float* b3a, const float* w1b, const float* b1b,
    const float* w2b, const float* b2b, const float* w3b, const float* b3b) {
    __shared__ __align__(16) float W[2 * WSTRIDE];
    const int t = threadIdx.x;
    {
        const float* srcs[12] = {w1a, b1a, w2a, b2a, w3a, b3a,
                                 w1b, b1b, w2b, b2b, w3b, b3b};
        const int ns[6] = {80, 40, 1600, 40, 40, 1};
        const int offs[6] = {0, 80, 120, 1720, 1760, 1800};
        for (int s = 0; s < 12; ++s) {
            const int base = (s / 6) * WSTRIDE + offs[s % 6];
            const int n4 = ns[s % 6] >> 2;
            const float4* src4 = (const float4*)srcs[s];
            float4* dst4 = (float4*)(W + base);
            for (int q = t; q < n4; q += 64) dst4[q] = src4[q];
        }
        if (t == 0) {
            W[1800] = b3a[0];
            W[WSTRIDE + 1800] = b3b[0];
        }
    }
    __syncthreads();

    const int atom = blockIdx.x * 16 + (t >> 2);
    const int net = (t >> 1) & 1;
    const int half = t & 1;
    const float* P = W + net * WSTRIDE;

    // g0 = 0.5 (rectangle -> triangle) * 2^(1-zeta)
    const float g0 = 0.6597539553864471f * ang[atom];
    const float g1 = rad[atom];

    float h1[40];
#pragma unroll
    for (int u = 0; u < 40; ++u) {
        float z = fmaf(P[2 * u], g0, fmaf(P[2 * u + 1], g1, P[80 + u]));
        h1[u] = 1.0f / fmaf(z, z, 1.0f);
    }

    float acc = half ? 0.0f : P[1800];
    const int v0 = half * 20;
    for (int v2 = v0; v2 < v0 + 20; ++v2) {
        const float4* row = (const float4*)(P + 120 + v2 * 40);
        float z0 = P[1720 + v2], z1 = 0.0f, z2 = 0.0f, z3 = 0.0f;
#pragma unroll
        for (int q = 0; q < 10; ++q) {
            float4 r = row[q];
            z0 = fmaf(r.x, h1[4 * q + 0], z0);
            z1 = fmaf(r.y, h1[4 * q + 1], z1);
            z2 = fmaf(r.z, h1[4 * q + 2], z2);
            z3 = fmaf(r.w, h1[4 * q + 3], z3);
        }
        float z = (z0 + z1) + (z2 + z3);
        float h = 1.0f / fmaf(z, z, 1.0f);
        acc = fmaf(P[1760 + v2], h, acc);
    }
    acc += __shfl_down(acc, 1, 64);

    if (half == 0 && net == ((atom == 8) ? 1 : 0)) out[atom] = acc;
}

extern "C" void kernel_launch(void* const* d_in, const int* in_sizes, int n_in,
                              void* d_out, int out_size, void* d_ws, size_t ws_size,
                              hipStream_t stream) {
    const float* x = (const float*)d_in[0];
    const float* w1a = (const float*)d_in[1];
    const float* b1a = (const float*)d_in[2];
    const float* w2a = (const float*)d_in[3];
    const float* b2a = (const float*)d_in[4];
    const float* w3a = (const float*)d_in[5];
    const float* b3a = (const float*)d_in[6];
    const float* w1b = (const float*)d_in[7];
    const float* b1b = (const float*)d_in[8];
    const float* w2b = (const float*)d_in[9];
    const float* b2b = (const float*)d_in[10];
    const float* w3b = (const float*)d_in[11];
    const float* b3b = (const float*)d_in[12];
    float* out = (float*)d_out;

    // ws layout (float offsets): A[147456] | nbr4[147456*4] | nbrJ[147456] |
    //                            rad[384] | ang[384] | cnt[384]
    float* ws = (float*)d_ws;
    float* A = ws;
    float4* nbr4 = (float4*)(ws + 147456);          // 16B-aligned (589824 B)
    int* nbrJ = (int*)(ws + 147456 + 4 * 147456);
    float* rad = ws + 147456 * 6;
    float* ang = rad + 384;
    int* cnt = (int*)(ang + 384);

    hipLaunchKernelGGL(pair_kernel, dim3(N), dim3(128), 0, stream,
                       x, A, nbr4, nbrJ, cnt, rad, ang);
    hipLaunchKernelGGL(ang_kernel, dim3(N, 8), dim3(256), 0, stream,
                       A, nbr4, nbrJ, cnt, ang);
    hipLaunchKernelGGL(mlp_kernel, dim3(24), dim3(64), 0, stream,
                       ang, rad, out,
                       w1a, b1a, w2a, b2a, w3a, b3a,
                       w1b, b1b, w2b, b2b, w3b, b3b);
}

// Round 6
// 112.756 us; speedup vs baseline: 1.1374x; 1.1374x over previous
//
#include <hip/hip_runtime.h>
#include <math.h>

#define N 384
#define EPSA 1e-4f   // drop A below this; dropped-sum contribution to ang ~1e-3
                     // (A_ij<eps => D_ij>~4.05 => partner products crushed by Gaussians)

#if __has_builtin(__builtin_amdgcn_logf) && __has_builtin(__builtin_amdgcn_exp2f)
#define LOG2F(x) __builtin_amdgcn_logf(x)
#define EXP2F(x) __builtin_amdgcn_exp2f(x)
#else
#define LOG2F(x) __log2f(x)
#define EXP2F(x) __expf(0.69314718056f * (x))
#endif

__device__ __forceinline__ float wave_reduce(float v) {
#pragma unroll
    for (int o = 32; o > 0; o >>= 1) v += __shfl_down(v, o, 64);
    return v;
}

// ---------------- Kernel 1: pairs + sorted neighbor compaction ----------------
// block per atom i (128 thr): dense A row (for gathers), rad[i], ang[i]=0,
// and a SORTED compact neighbor list: nbr4[slot]=(ux,uy,uz,A_ij), nbrJ[slot]=j.
__global__ __launch_bounds__(128) void pair_kernel(
    const float* __restrict__ x, float* __restrict__ A,
    float4* __restrict__ nbr4, int* __restrict__ nbrJ, int* __restrict__ cnt,
    float* __restrict__ rad, float* __restrict__ ang) {
    const int i = blockIdx.x;
    const int t = threadIdx.x;
    const int lane = t & 63, w = t >> 6;
    const float xi0 = x[3 * i + 0], xi1 = x[3 * i + 1], xi2 = x[3 * i + 2];

    float racc = 0.0f;
    float4 val[3];
    int keep[3];
#pragma unroll
    for (int r = 0; r < 3; ++r) {
        const int j = t + 128 * r;
        float dx = xi0 - x[3 * j + 0];
        float dy = xi1 - x[3 * j + 1];
        float dz = xi2 - x[3 * j + 2];
        float d2 = dx * dx + dy * dy + dz * dz;
        float a = 0.0f, rr = 0.0f, inv = 0.0f;
        if (j != i) {
            float d = sqrtf(d2);
            if (d <= 6.0f) {
                float fc = 0.5f * (__cosf(0.52359877559829887f * d) + 1.0f);
                a = __expf(-0.5f * d2) * fc;
                float dm = d - 1.0f;  // RS = 1
                rr = __expf(-0.5f * dm * dm) * fc;
            }
            inv = rsqrtf(d2);
        }
        A[i * N + j] = a;
        racc += rr;
        val[r] = make_float4(dx * inv, dy * inv, dz * inv, a);
        keep[r] = (a > EPSA) ? 1 : 0;
    }

    // sorted compaction: chunk c = (j>>6) = w + 2r; ballot + prefix per chunk
    __shared__ int bcnt[6], bbase[6];
    int pfx[3];
#pragma unroll
    for (int r = 0; r < 3; ++r) {
        unsigned long long m = __ballot(keep[r]);
        pfx[r] = __popcll(m & ((1ull << lane) - 1ull));
        if (lane == 0) bcnt[w + 2 * r] = __popcll(m);
    }
    __syncthreads();
    if (t == 0) {
        int s = 0;
#pragma unroll
        for (int c = 0; c < 6; ++c) { bbase[c] = s; s += bcnt[c]; }
        cnt[i] = s;
        ang[i] = 0.0f;
    }
    __syncthreads();
#pragma unroll
    for (int r = 0; r < 3; ++r) {
        if (keep[r]) {
            const int slot = bbase[w + 2 * r] + pfx[r];
            nbr4[i * N + slot] = val[r];
            nbrJ[i * N + slot] = t + 128 * r;
        }
    }

    __shared__ float red[2];
    float v = wave_reduce(racc);
    if (lane == 0) red[w] = v;
    __syncthreads();
    if (t == 0) rad[i] = red[0] + red[1];
}

// ---------------- Kernel 2: angular sum over compact rectangle ----------------
// grid (N, 4): jc splits the compact j range in 4. 256 threads, one compact-k
// per thread per 256-chunk (u_k pre-scaled by -lambda, A_ik in registers).
// Full rectangle over compact list = 2x triangle; 0.5 folded into mlp's g0.
// Inner loop is branch-free (clamped prefetch index) for compiler unrolling.
// NOTE: no fmax clamp on b: b = 1 + 0.8*cos(theta) >= 0.2 > 1e-6 always.
__global__ __launch_bounds__(256) void ang_kernel(
    const float* __restrict__ A, const float4* __restrict__ nbr4,
    const int* __restrict__ nbrJ, const int* __restrict__ cnt,
    float* __restrict__ ang) {
    const int i = blockIdx.x;
    const int jc = blockIdx.y;
    const int t = threadIdx.x;
    const int n = cnt[i];
    if (n == 0) return;

    const int qn = (n + 3) >> 2;           // j per jc block
    const int js = jc * qn;
    const int je = min(js + qn, n);
    if (js >= je) return;
    const int m = je - js;

    __shared__ __align__(16) float4 sh4[96];
    __shared__ int shJN[96];               // j*N (row offset), wave-uniform use
    for (int s = t; s < m; s += 256) {
        sh4[s] = nbr4[i * N + js + s];
        shJN[s] = nbrJ[i * N + js + s] * N;
    }
    __syncthreads();

    float acc = 0.0f;
    for (int ks0 = 0; ks0 < n; ks0 += 256) {  // one iter unless n > 256 (rare)
        const int ks = ks0 + t;
        const int valid = ks < n;
        float4 K = valid ? nbr4[i * N + ks] : make_float4(0.f, 0.f, 0.f, 0.f);
        const int kcol = valid ? nbrJ[i * N + ks] : 0;
        // fold -lambda: base = 1 + 0.8*cos = 1 + u_j . (-0.8*u_k)
        const float kx = -0.8f * K.x, ky = -0.8f * K.y, kz = -0.8f * K.z;
        const float kA = K.w;
        const float* Acol = A + kcol;

        float cacc = 0.0f;
        int ro = __builtin_amdgcn_readfirstlane(shJN[0]);
        float a = Acol[ro];                // A_jk gather: sorted kcol, few lines
#pragma unroll 2
        for (int s = 0; s < m; ++s) {
            int rn = __builtin_amdgcn_readfirstlane(shJN[min(s + 1, m - 1)]);
            float an = Acol[rn];           // prefetch (redundant on last iter)
            float4 J = sh4[s];             // LDS broadcast (conflict-free)
            float b = fmaf(J.x, kx, fmaf(J.y, ky, fmaf(J.z, kz, 1.0f)));
            float p = EXP2F(0.6f * LOG2F(b));   // base^zeta
            cacc = fmaf(J.w * a, p, cacc);
            a = an;
        }
        acc = fmaf(kA, cacc, acc);
    }

    __shared__ float red[4];
    float v = wave_reduce(acc);
    if ((t & 63) == 0) red[t >> 6] = v;
    __syncthreads();
    if (t == 0) atomicAdd(&ang[i], red[0] + red[1] + red[2] + red[3]);
}

// ---------------- Kernel 3: MLPs + select ----------------
// 24 blocks x 64 threads; t = local*4 + net*2 + half; halves split the 40-row
// hidden-2 loop, combined via shfl. Per-net LDS stride 1804 floats:
//   w1[80]@0  b1[40]@80  w2[1600]@120  b2[40]@1720  w3[40]@1760  b3[1]@1800
#define WSTRIDE 1804
__global__ __launch_bounds__(64) void mlp_kernel(
    const float* __restrict__ ang, const float* __restrict__ rad,
    float* __restrict__ out,
    const float* w1a, const float* b1a, const float* w2a, const float* b2a,
    const float* w3a, const float* b3a, const float* w1b, const float* b1b,
    const float* w2b, const float* b2b, const float* w3b, const float* b3b) {
    __shared__ __align__(16) float W[2 * WSTRIDE];
    const int t = threadIdx.x;
    {
        const float* srcs[12] = {w1a, b1a, w2a, b2a, w3a, b3a,
                                 w1b, b1b, w2b, b2b, w3b, b3b};
        const int ns[6] = {80, 40, 1600, 40, 40, 1};
        const int offs[6] = {0, 80, 120, 1720, 1760, 1800};
        for (int s = 0; s < 12; ++s) {
            const int base = (s / 6) * WSTRIDE + offs[s % 6];
            const int n4 = ns[s % 6] >> 2;
            const float4* src4 = (const float4*)srcs[s];
            float4* dst4 = (float4*)(W + base);
            for (int q = t; q < n4; q += 64) dst4[q] = src4[q];
        }
        if (t == 0) {
            W[1800] = b3a[0];
            W[WSTRIDE + 1800] = b3b[0];
        }
    }
    __syncthreads();

    const int atom = blockIdx.x * 16 + (t >> 2);
    const int net = (t >> 1) & 1;
    const int half = t & 1;
    const float* P = W + net * WSTRIDE;

    // g0 = 0.5 (rectangle -> triangle) * 2^(1-zeta)
    const float g0 = 0.6597539553864471f * ang[atom];
    const float g1 = rad[atom];

    float h1[40];
#pragma unroll
    for (int u = 0; u < 40; ++u) {
        float z = fmaf(P[2 * u], g0, fmaf(P[2 * u + 1], g1, P[80 + u]));
        h1[u] = 1.0f / fmaf(z, z, 1.0f);
    }

    float acc = half ? 0.0f : P[1800];
    const int v0 = half * 20;
    for (int v2 = v0; v2 < v0 + 20; ++v2) {
        const float4* row = (const float4*)(P + 120 + v2 * 40);
        float z0 = P[1720 + v2], z1 = 0.0f, z2 = 0.0f, z3 = 0.0f;
#pragma unroll
        for (int q = 0; q < 10; ++q) {
            float4 r = row[q];
            z0 = fmaf(r.x, h1[4 * q + 0], z0);
            z1 = fmaf(r.y, h1[4 * q + 1], z1);
            z2 = fmaf(r.z, h1[4 * q + 2], z2);
            z3 = fmaf(r.w, h1[4 * q + 3], z3);
        }
        float z = (z0 + z1) + (z2 + z3);
        float h = 1.0f / fmaf(z, z, 1.0f);
        acc = fmaf(P[1760 + v2], h, acc);
    }
    acc += __shfl_down(acc, 1, 64);

    if (half == 0 && net == ((atom == 8) ? 1 : 0)) out[atom] = acc;
}

extern "C" void kernel_launch(void* const* d_in, const int* in_sizes, int n_in,
                              void* d_out, int out_size, void* d_ws, size_t ws_size,
                              hipStream_t stream) {
    const float* x = (const float*)d_in[0];
    const float* w1a = (const float*)d_in[1];
    const float* b1a = (const float*)d_in[2];
    const float* w2a = (const float*)d_in[3];
    const float* b2a = (const float*)d_in[4];
    const float* w3a = (const float*)d_in[5];
    const float* b3a = (const float*)d_in[6];
    const float* w1b = (const float*)d_in[7];
    const float* b1b = (const float*)d_in[8];
    const float* w2b = (const float*)d_in[9];
    const float* b2b = (const float*)d_in[10];
    const float* w3b = (const float*)d_in[11];
    const float* b3b = (const float*)d_in[12];
    float* out = (float*)d_out;

    // ws layout (float offsets): A[147456] | nbr4[147456*4] | nbrJ[147456] |
    //                            rad[384] | ang[384] | cnt[384]
    float* ws = (float*)d_ws;
    float* A = ws;
    float4* nbr4 = (float4*)(ws + 147456);          // 16B-aligned
    int* nbrJ = (int*)(ws + 147456 + 4 * 147456);
    float* rad = ws + 147456 * 6;
    float* ang = rad + 384;
    int* cnt = (int*)(ang + 384);

    hipLaunchKernelGGL(pair_kernel, dim3(N), dim3(128), 0, stream,
                       x, A, nbr4, nbrJ, cnt, rad, ang);
    hipLaunchKernelGGL(ang_kernel, dim3(N, 4), dim3(256), 0, stream,
                       A, nbr4, nbrJ, cnt, ang);
    hipLaunchKernelGGL(mlp_kernel, dim3(24), dim3(64), 0, stream,
                       ang, rad, out,
                       w1a, b1a, w2a, b2a, w3a, b3a,
                       w1b, b1b, w2b, b2b, w3b, b3b);
}

// Round 7
// 111.041 us; speedup vs baseline: 1.1550x; 1.0154x over previous
//
#include <hip/hip_runtime.h>
#include <math.h>

#define N 384
#define EPSA 1e-4f   // drop A below this; dropped-sum contribution to ang ~1e-3

#if __has_builtin(__builtin_amdgcn_logf) && __has_builtin(__builtin_amdgcn_exp2f)
#define LOG2F(x) __builtin_amdgcn_logf(x)
#define EXP2F(x) __builtin_amdgcn_exp2f(x)
#else
#define LOG2F(x) __log2f(x)
#define EXP2F(x) __expf(0.69314718056f * (x))
#endif

__device__ __forceinline__ float wave_reduce(float v) {
#pragma unroll
    for (int o = 32; o > 0; o >>= 1) v += __shfl_down(v, o, 64);
    return v;
}

// ---------------- Kernel 1: pairs + sorted neighbor compaction ----------------
// block per atom i (128 thr): dense A row (for gathers), rad[i], ang[i]=0, and a
// SORTED compact neighbor list padded to a multiple of 8 with self-masking zero
// entries (val=0 => J.w=0 / kA=0; nbrJ=i => gather hits A[i*N+k], masked anyway).
__global__ __launch_bounds__(128) void pair_kernel(
    const float* __restrict__ x, float* __restrict__ A,
    float4* __restrict__ nbr4, int* __restrict__ nbrJ, int* __restrict__ cnt,
    float* __restrict__ rad, float* __restrict__ ang) {
    const int i = blockIdx.x;
    const int t = threadIdx.x;
    const int lane = t & 63, w = t >> 6;
    const float xi0 = x[3 * i + 0], xi1 = x[3 * i + 1], xi2 = x[3 * i + 2];

    float racc = 0.0f;
    float4 val[3];
    int keep[3];
#pragma unroll
    for (int r = 0; r < 3; ++r) {
        const int j = t + 128 * r;
        float dx = xi0 - x[3 * j + 0];
        float dy = xi1 - x[3 * j + 1];
        float dz = xi2 - x[3 * j + 2];
        float d2 = dx * dx + dy * dy + dz * dz;
        float a = 0.0f, rr = 0.0f, inv = 0.0f;
        if (j != i) {
            float d = sqrtf(d2);
            if (d <= 6.0f) {
                float fc = 0.5f * (__cosf(0.52359877559829887f * d) + 1.0f);
                a = __expf(-0.5f * d2) * fc;
                float dm = d - 1.0f;  // RS = 1
                rr = __expf(-0.5f * dm * dm) * fc;
            }
            inv = rsqrtf(d2);
        }
        A[i * N + j] = a;
        racc += rr;
        val[r] = make_float4(dx * inv, dy * inv, dz * inv, a);
        keep[r] = (a > EPSA) ? 1 : 0;
    }

    // sorted compaction: chunk c = (j>>6) = w + 2r; ballot + prefix per chunk
    __shared__ int bcnt[6], bbase[6], realn;
    int pfx[3];
#pragma unroll
    for (int r = 0; r < 3; ++r) {
        unsigned long long m = __ballot(keep[r]);
        pfx[r] = __popcll(m & ((1ull << lane) - 1ull));
        if (lane == 0) bcnt[w + 2 * r] = __popcll(m);
    }
    __syncthreads();
    if (t == 0) {
        int s = 0;
#pragma unroll
        for (int c = 0; c < 6; ++c) { bbase[c] = s; s += bcnt[c]; }
        realn = s;
        cnt[i] = (s + 7) & ~7;   // padded count (multiple of 8)
        ang[i] = 0.0f;
    }
    __syncthreads();
#pragma unroll
    for (int r = 0; r < 3; ++r) {
        if (keep[r]) {
            const int slot = bbase[w + 2 * r] + pfx[r];
            nbr4[i * N + slot] = val[r];
            nbrJ[i * N + slot] = t + 128 * r;
        }
    }
    // zero-pad to multiple of 8 (self-masking entries)
    const int rn = realn;
    const int np = (rn + 7) & ~7;
    if (t < np - rn) {
        nbr4[i * N + rn + t] = make_float4(0.f, 0.f, 0.f, 0.f);
        nbrJ[i * N + rn + t] = i;
    }

    __shared__ float red[2];
    float v = wave_reduce(racc);
    if (lane == 0) red[w] = v;
    __syncthreads();
    if (t == 0) rad[i] = red[0] + red[1];
}

// ---------------- Kernel 2: angular sum over compact rectangle ----------------
// grid (N, 4), 256 threads. One compact-k per thread (u_k pre-scaled by
// -lambda, A_ik in registers); j-side runs in batches of 8 with BLOCK-UNIFORM
// addresses -> s_load through the constant cache (no LDS, no readfirstlane
// chain): 8 independent A_jk gathers in flight, then 8 unrolled fmaf/log/exp
// iterations. Padded entries self-mask (J.w=0 or kA=0). Rectangle = 2x the
// triangle; 0.5 folded into mlp's g0. b = 1+0.8*cos >= 0.2, no clamp needed.
__global__ __launch_bounds__(256) void ang_kernel(
    const float* __restrict__ A, const float4* __restrict__ nbr4,
    const int* __restrict__ nbrJ, const int* __restrict__ cnt,
    float* __restrict__ ang) {
    const int i = blockIdx.x;
    const int jc = blockIdx.y;          // 0..3: batch-strided j split
    const int t = threadIdx.x;
    const int n = cnt[i];               // multiple of 8
    if (n == 0) return;
    const int iN = i * N;
    const int nb = n >> 3;              // number of 8-wide j batches

    float acc = 0.0f;
    for (int ks0 = 0; ks0 < n; ks0 += 256) {   // one iter unless n > 256
        const int ks = ks0 + t;
        const bool valid = ks < n;
        float4 K = valid ? nbr4[iN + ks] : make_float4(0.f, 0.f, 0.f, 0.f);
        const int kcol = valid ? nbrJ[iN + ks] : 0;
        const float kx = -0.8f * K.x, ky = -0.8f * K.y, kz = -0.8f * K.z;
        const float kA = K.w;
        const float* Acol = A + kcol;

        float cacc = 0.0f;
        for (int b = jc; b < nb; b += 4) {
            const int s0 = b << 3;
            float a8[8];
#pragma unroll
            for (int q = 0; q < 8; ++q)          // 8 gathers in flight
                a8[q] = Acol[nbrJ[iN + s0 + q] * N];
#pragma unroll
            for (int q = 0; q < 8; ++q) {
                float4 J = nbr4[iN + s0 + q];    // uniform -> s_load_dwordx4
                float bb = fmaf(J.x, kx, fmaf(J.y, ky, fmaf(J.z, kz, 1.0f)));
                float p = EXP2F(0.6f * LOG2F(bb));   // base^zeta
                cacc = fmaf(J.w * a8[q], p, cacc);
            }
        }
        acc = fmaf(kA, cacc, acc);
    }

    __shared__ float red[4];
    float v = wave_reduce(acc);
    if ((t & 63) == 0) red[t >> 6] = v;
    __syncthreads();
    if (t == 0) atomicAdd(&ang[i], red[0] + red[1] + red[2] + red[3]);
}

// ---------------- Kernel 3: MLPs + select ----------------
// 24 blocks x 64 threads; t = local*4 + net*2 + half; halves split the 40-row
// hidden-2 loop, combined via shfl. Per-net LDS stride 1804 floats:
//   w1[80]@0  b1[40]@80  w2[1600]@120  b2[40]@1720  w3[40]@1760  b3[1]@1800
#define WSTRIDE 1804
__global__ __launch_bounds__(64) void mlp_kernel(
    const float* __restrict__ ang, const float* __restrict__ rad,
    float* __restrict__ out,
    const float* w1a, const float* b1a, const float* w2a, const float* b2a,
    const float* w3a, const float* b3a, const float* w1b, const float* b1b,
    const float* w2b, const float* b2b, const float* w3b, const float* b3b) {
    __shared__ __align__(16) float W[2 * WSTRIDE];
    const int t = threadIdx.x;
    {
        const float* srcs[12] = {w1a, b1a, w2a, b2a, w3a, b3a,
                                 w1b, b1b, w2b, b2b, w3b, b3b};
        const int ns[6] = {80, 40, 1600, 40, 40, 1};
        const int offs[6] = {0, 80, 120, 1720, 1760, 1800};
        for (int s = 0; s < 12; ++s) {
            const int base = (s / 6) * WSTRIDE + offs[s % 6];
            const int n4 = ns[s % 6] >> 2;
            const float4* src4 = (const float4*)srcs[s];
            float4* dst4 = (float4*)(W + base);
            for (int q = t; q < n4; q += 64) dst4[q] = src4[q];
        }
        if (t == 0) {
            W[1800] = b3a[0];
            W[WSTRIDE + 1800] = b3b[0];
        }
    }
    __syncthreads();

    const int atom = blockIdx.x * 16 + (t >> 2);
    const int net = (t >> 1) & 1;
    const int half = t & 1;
    const float* P = W + net * WSTRIDE;

    // g0 = 0.5 (rectangle -> triangle) * 2^(1-zeta)
    const float g0 = 0.6597539553864471f * ang[atom];
    const float g1 = rad[atom];

    float h1[40];
#pragma unroll
    for (int u = 0; u < 40; ++u) {
        float z = fmaf(P[2 * u], g0, fmaf(P[2 * u + 1], g1, P[80 + u]));
        h1[u] = 1.0f / fmaf(z, z, 1.0f);
    }

    float acc = half ? 0.0f : P[1800];
    const int v0 = half * 20;
    for (int v2 = v0; v2 < v0 + 20; ++v2) {
        const float4* row = (const float4*)(P + 120 + v2 * 40);
        float z0 = P[1720 + v2], z1 = 0.0f, z2 = 0.0f, z3 = 0.0f;
#pragma unroll
        for (int q = 0; q < 10; ++q) {
            float4 r = row[q];
            z0 = fmaf(r.x, h1[4 * q + 0], z0);
            z1 = fmaf(r.y, h1[4 * q + 1], z1);
            z2 = fmaf(r.z, h1[4 * q + 2], z2);
            z3 = fmaf(r.w, h1[4 * q + 3], z3);
        }
        float z = (z0 + z1) + (z2 + z3);
        float h = 1.0f / fmaf(z, z, 1.0f);
        acc = fmaf(P[1760 + v2], h, acc);
    }
    acc += __shfl_down(acc, 1, 64);

    if (half == 0 && net == ((atom == 8) ? 1 : 0)) out[atom] = acc;
}

extern "C" void kernel_launch(void* const* d_in, const int* in_sizes, int n_in,
                              void* d_out, int out_size, void* d_ws, size_t ws_size,
                              hipStream_t stream) {
    const float* x = (const float*)d_in[0];
    const float* w1a = (const float*)d_in[1];
    const float* b1a = (const float*)d_in[2];
    const float* w2a = (const float*)d_in[3];
    const float* b2a = (const float*)d_in[4];
    const float* w3a = (const float*)d_in[5];
    const float* b3a = (const float*)d_in[6];
    const float* w1b = (const float*)d_in[7];
    const float* b1b = (const float*)d_in[8];
    const float* w2b = (const float*)d_in[9];
    const float* b2b = (const float*)d_in[10];
    const float* w3b = (const float*)d_in[11];
    const float* b3b = (const float*)d_in[12];
    float* out = (float*)d_out;

    // ws layout (float offsets): A[147456] | nbr4[147456*4] | nbrJ[147456] |
    //                            rad[384] | ang[384] | cnt[384]
    float* ws = (float*)d_ws;
    float* A = ws;
    float4* nbr4 = (float4*)(ws + 147456);          // 16B-aligned
    int* nbrJ = (int*)(ws + 147456 + 4 * 147456);
    float* rad = ws + 147456 * 6;
    float* ang = rad + 384;
    int* cnt = (int*)(ang + 384);

    hipLaunchKernelGGL(pair_kernel, dim3(N), dim3(128), 0, stream,
                       x, A, nbr4, nbrJ, cnt, rad, ang);
    hipLaunchKernelGGL(ang_kernel, dim3(N, 4), dim3(256), 0, stream,
                       A, nbr4, nbrJ, cnt, ang);
    hipLaunchKernelGGL(mlp_kernel, dim3(24), dim3(64), 0, stream,
                       ang, rad, out,
                       w1a, b1a, w2a, b2a, w3a, b3a,
                       w1b, b1b, w2b, b2b, w3b, b3b);
}

// Round 8
// 106.019 us; speedup vs baseline: 1.2097x; 1.0474x over previous
//
#include <hip/hip_runtime.h>
#include <math.h>

#define N 384
#define EPSA 4e-4f   // drop A below this (cut D ~3.75); dropped-sum error ~1e-3,
                     // vs 1.76e-2 threshold (absmax was 0.0 at eps=1e-4)

#if __has_builtin(__builtin_amdgcn_logf) && __has_builtin(__builtin_amdgcn_exp2f)
#define LOG2F(x) __builtin_amdgcn_logf(x)
#define EXP2F(x) __builtin_amdgcn_exp2f(x)
#else
#define LOG2F(x) __log2f(x)
#define EXP2F(x) __expf(0.69314718056f * (x))
#endif

__device__ __forceinline__ float wave_reduce(float v) {
#pragma unroll
    for (int o = 32; o > 0; o >>= 1) v += __shfl_down(v, o, 64);
    return v;
}

// ---------------- Kernel 1: pairs + sorted neighbor compaction ----------------
// block per atom i (128 thr): dense A row (for gathers), rad[i], ang[i]=0, and a
// SORTED compact neighbor list padded to a multiple of 8 with self-masking zero
// entries (val=0 => J.w=0 / kA=0; nbrJ=i => gather hits A[i*N+k], masked anyway).
__global__ __launch_bounds__(128) void pair_kernel(
    const float* __restrict__ x, float* __restrict__ A,
    float4* __restrict__ nbr4, int* __restrict__ nbrJ, int* __restrict__ cnt,
    float* __restrict__ rad, float* __restrict__ ang) {
    const int i = blockIdx.x;
    const int t = threadIdx.x;
    const int lane = t & 63, w = t >> 6;
    const float xi0 = x[3 * i + 0], xi1 = x[3 * i + 1], xi2 = x[3 * i + 2];

    float racc = 0.0f;
    float4 val[3];
    int keep[3];
#pragma unroll
    for (int r = 0; r < 3; ++r) {
        const int j = t + 128 * r;
        float dx = xi0 - x[3 * j + 0];
        float dy = xi1 - x[3 * j + 1];
        float dz = xi2 - x[3 * j + 2];
        float d2 = dx * dx + dy * dy + dz * dz;
        float a = 0.0f, rr = 0.0f, inv = 0.0f;
        if (j != i) {
            float d = sqrtf(d2);
            if (d <= 6.0f) {
                float fc = 0.5f * (__cosf(0.52359877559829887f * d) + 1.0f);
                a = __expf(-0.5f * d2) * fc;
                float dm = d - 1.0f;  // RS = 1
                rr = __expf(-0.5f * dm * dm) * fc;
            }
            inv = rsqrtf(d2);
        }
        A[i * N + j] = a;
        racc += rr;
        val[r] = make_float4(dx * inv, dy * inv, dz * inv, a);
        keep[r] = (a > EPSA) ? 1 : 0;
    }

    // sorted compaction: chunk c = (j>>6) = w + 2r; ballot + prefix per chunk
    __shared__ int bcnt[6], bbase[6], realn;
    int pfx[3];
#pragma unroll
    for (int r = 0; r < 3; ++r) {
        unsigned long long m = __ballot(keep[r]);
        pfx[r] = __popcll(m & ((1ull << lane) - 1ull));
        if (lane == 0) bcnt[w + 2 * r] = __popcll(m);
    }
    __syncthreads();
    if (t == 0) {
        int s = 0;
#pragma unroll
        for (int c = 0; c < 6; ++c) { bbase[c] = s; s += bcnt[c]; }
        realn = s;
        cnt[i] = (s + 7) & ~7;   // padded count (multiple of 8)
        ang[i] = 0.0f;
    }
    __syncthreads();
#pragma unroll
    for (int r = 0; r < 3; ++r) {
        if (keep[r]) {
            const int slot = bbase[w + 2 * r] + pfx[r];
            nbr4[i * N + slot] = val[r];
            nbrJ[i * N + slot] = t + 128 * r;
        }
    }
    // zero-pad to multiple of 8 (self-masking entries)
    const int rn = realn;
    const int np = (rn + 7) & ~7;
    if (t < np - rn) {
        nbr4[i * N + rn + t] = make_float4(0.f, 0.f, 0.f, 0.f);
        nbrJ[i * N + rn + t] = i;
    }

    __shared__ float red[2];
    float v = wave_reduce(racc);
    if (lane == 0) red[w] = v;
    __syncthreads();
    if (t == 0) rad[i] = red[0] + red[1];
}

// ---------------- Kernel 2: angular sum over compact rectangle ----------------
// grid (N, 4), 256 threads. One compact-k per thread (u_k pre-scaled by
// -lambda, A_ik in registers); j-side runs in batches of 8 with BLOCK-UNIFORM
// addresses -> s_load through the constant cache: 8 independent A_jk gathers in
// flight, then 8 unrolled fmaf/log/exp iterations. Padded entries self-mask.
// WAVE-UNIFORM EARLY SKIP: waves whose entire k-range is >= n skip the j-loop
// (n is block-uniform, t&~63 is wave-uniform -> no divergence).
// Rectangle = 2x triangle; 0.5 folded into mlp's g0. b = 1+0.8*cos >= 0.2.
__global__ __launch_bounds__(256) void ang_kernel(
    const float* __restrict__ A, const float4* __restrict__ nbr4,
    const int* __restrict__ nbrJ, const int* __restrict__ cnt,
    float* __restrict__ ang) {
    const int i = blockIdx.x;
    const int jc = blockIdx.y;          // 0..3: batch-strided j split
    const int t = threadIdx.x;
    const int n = cnt[i];               // multiple of 8
    const int iN = i * N;
    const int nb = n >> 3;              // number of 8-wide j batches

    float acc = 0.0f;
    if (n != 0) {
        for (int ks0 = 0; ks0 < n; ks0 += 256) {   // one iter unless n > 256
            if (ks0 + (t & ~63) >= n) break;       // wave-uniform skip
            const int ks = ks0 + t;
            const bool valid = ks < n;
            float4 K = valid ? nbr4[iN + ks] : make_float4(0.f, 0.f, 0.f, 0.f);
            const int kcol = valid ? nbrJ[iN + ks] : 0;
            const float kx = -0.8f * K.x, ky = -0.8f * K.y, kz = -0.8f * K.z;
            const float kA = K.w;
            const float* Acol = A + kcol;

            float cacc = 0.0f;
            for (int b = jc; b < nb; b += 4) {
                const int s0 = b << 3;
                float a8[8];
#pragma unroll
                for (int q = 0; q < 8; ++q)          // 8 gathers in flight
                    a8[q] = Acol[nbrJ[iN + s0 + q] * N];
#pragma unroll
                for (int q = 0; q < 8; ++q) {
                    float4 J = nbr4[iN + s0 + q];    // uniform -> s_load_dwordx4
                    float bb = fmaf(J.x, kx, fmaf(J.y, ky, fmaf(J.z, kz, 1.0f)));
                    float p = EXP2F(0.6f * LOG2F(bb));   // base^zeta
                    cacc = fmaf(J.w * a8[q], p, cacc);
                }
            }
            acc = fmaf(kA, cacc, acc);
        }
    }

    __shared__ float red[4];
    float v = wave_reduce(acc);
    if ((t & 63) == 0) red[t >> 6] = v;
    __syncthreads();
    if (t == 0) {
        float s = red[0] + red[1] + red[2] + red[3];
        if (s != 0.0f) atomicAdd(&ang[i], s);
        else if (jc == 0) atomicAdd(&ang[i], 0.0f);  // keep ang defined
    }
}

// ---------------- Kernel 3: MLPs + select ----------------
// 24 blocks x 64 threads; t = local*4 + net*2 + half; halves split the 40-row
// hidden-2 loop, combined via shfl. Per-net LDS stride 1804 floats:
//   w1[80]@0  b1[40]@80  w2[1600]@120  b2[40]@1720  w3[40]@1760  b3[1]@1800
#define WSTRIDE 1804
__global__ __launch_bounds__(64) void mlp_kernel(
    const float* __restrict__ ang, const float* __restrict__ rad,
    float* __restrict__ out,
    const float* w1a, const float* b1a, const float* w2a, const float* b2a,
    const float* w3a, const float* b3a, const float* w1b, const float* b1b,
    const float* w2b, const float* b2b, const float* w3b, const float* b3b) {
    __shared__ __align__(16) float W[2 * WSTRIDE];
    const int t = threadIdx.x;
    {
        const float* srcs[12] = {w1a, b1a, w2a, b2a, w3a, b3a,
                                 w1b, b1b, w2b, b2b, w3b, b3b};
        const int ns[6] = {80, 40, 1600, 40, 40, 1};
        const int offs[6] = {0, 80, 120, 1720, 1760, 1800};
        for (int s = 0; s < 12; ++s) {
            const int base = (s / 6) * WSTRIDE + offs[s % 6];
            const int n4 = ns[s % 6] >> 2;
            const float4* src4 = (const float4*)srcs[s];
            float4* dst4 = (float4*)(W + base);
            for (int q = t; q < n4; q += 64) dst4[q] = src4[q];
        }
        if (t == 0) {
            W[1800] = b3a[0];
            W[WSTRIDE + 1800] = b3b[0];
        }
    }
    __syncthreads();

    const int atom = blockIdx.x * 16 + (t >> 2);
    const int net = (t >> 1) & 1;
    const int half = t & 1;
    const float* P = W + net * WSTRIDE;

    // g0 = 0.5 (rectangle -> triangle) * 2^(1-zeta)
    const float g0 = 0.6597539553864471f * ang[atom];
    const float g1 = rad[atom];

    float h1[40];
#pragma unroll
    for (int u = 0; u < 40; ++u) {
        float z = fmaf(P[2 * u], g0, fmaf(P[2 * u + 1], g1, P[80 + u]));
        h1[u] = 1.0f / fmaf(z, z, 1.0f);
    }

    float acc = half ? 0.0f : P[1800];
    const int v0 = half * 20;
    for (int v2 = v0; v2 < v0 + 20; ++v2) {
        const float4* row = (const float4*)(P + 120 + v2 * 40);
        float z0 = P[1720 + v2], z1 = 0.0f, z2 = 0.0f, z3 = 0.0f;
#pragma unroll
        for (int q = 0; q < 10; ++q) {
            float4 r = row[q];
            z0 = fmaf(r.x, h1[4 * q + 0], z0);
            z1 = fmaf(r.y, h1[4 * q + 1], z1);
            z2 = fmaf(r.z, h1[4 * q + 2], z2);
            z3 = fmaf(r.w, h1[4 * q + 3], z3);
        }
        float z = (z0 + z1) + (z2 + z3);
        float h = 1.0f / fmaf(z, z, 1.0f);
        acc = fmaf(P[1760 + v2], h, acc);
    }
    acc += __shfl_down(acc, 1, 64);

    if (half == 0 && net == ((atom == 8) ? 1 : 0)) out[atom] = acc;
}

extern "C" void kernel_launch(void* const* d_in, const int* in_sizes, int n_in,
                              void* d_out, int out_size, void* d_ws, size_t ws_size,
                              hipStream_t stream) {
    const float* x = (const float*)d_in[0];
    const float* w1a = (const float*)d_in[1];
    const float* b1a = (const float*)d_in[2];
    const float* w2a = (const float*)d_in[3];
    const float* b2a = (const float*)d_in[4];
    const float* w3a = (const float*)d_in[5];
    const float* b3a = (const float*)d_in[6];
    const float* w1b = (const float*)d_in[7];
    const float* b1b = (const float*)d_in[8];
    const float* w2b = (const float*)d_in[9];
    const float* b2b = (const float*)d_in[10];
    const float* w3b = (const float*)d_in[11];
    const float* b3b = (const float*)d_in[12];
    float* out = (float*)d_out;

    // ws layout (float offsets): A[147456] | nbr4[147456*4] | nbrJ[147456] |
    //                            rad[384] | ang[384] | cnt[384]
    float* ws = (float*)d_ws;
    float* A = ws;
    float4* nbr4 = (float4*)(ws + 147456);          // 16B-aligned
    int* nbrJ = (int*)(ws + 147456 + 4 * 147456);
    float* rad = ws + 147456 * 6;
    float* ang = rad + 384;
    int* cnt = (int*)(ang + 384);

    hipLaunchKernelGGL(pair_kernel, dim3(N), dim3(128), 0, stream,
                       x, A, nbr4, nbrJ, cnt, rad, ang);
    hipLaunchKernelGGL(ang_kernel, dim3(N, 4), dim3(256), 0, stream,
                       A, nbr4, nbrJ, cnt, ang);
    hipLaunchKernelGGL(mlp_kernel, dim3(24), dim3(64), 0, stream,
                       ang, rad, out,
                       w1a, b1a, w2a, b2a, w3a, b3a,
                       w1b, b1b, w2b, b2b, w3b, b3b);
}

// Round 9
// 102.266 us; speedup vs baseline: 1.2541x; 1.0367x over previous
//
#include <hip/hip_runtime.h>
#include <math.h>

#define N 384
#define EPSA 4e-4f   // drop A below this; dropped-sum error ~1e-3 vs 1.76e-2 threshold

#if __has_builtin(__builtin_amdgcn_logf) && __has_builtin(__builtin_amdgcn_exp2f)
#define LOG2F(x) __builtin_amdgcn_logf(x)
#define EXP2F(x) __builtin_amdgcn_exp2f(x)
#else
#define LOG2F(x) __log2f(x)
#define EXP2F(x) __expf(0.69314718056f * (x))
#endif

__device__ __forceinline__ float wave_reduce(float v) {
#pragma unroll
    for (int o = 32; o > 0; o >>= 1) v += __shfl_down(v, o, 64);
    return v;
}

// ---------------- Kernel 1: pairs + sorted neighbor compaction ----------------
// block per atom i (128 thr): dense A row (for gathers), rad[i], ang[i]=0,
// done[i]=0, and a SORTED compact neighbor list padded to a multiple of 8 with
// self-masking zero entries (val=0 => masked; nbrJ=i => gather hits diag, masked).
__global__ __launch_bounds__(128) void pair_kernel(
    const float* __restrict__ x, float* __restrict__ A,
    float4* __restrict__ nbr4, int* __restrict__ nbrJ, int* __restrict__ cnt,
    float* __restrict__ rad, float* __restrict__ ang, int* __restrict__ done) {
    const int i = blockIdx.x;
    const int t = threadIdx.x;
    const int lane = t & 63, w = t >> 6;
    const float xi0 = x[3 * i + 0], xi1 = x[3 * i + 1], xi2 = x[3 * i + 2];

    float racc = 0.0f;
    float4 val[3];
    int keep[3];
#pragma unroll
    for (int r = 0; r < 3; ++r) {
        const int j = t + 128 * r;
        float dx = xi0 - x[3 * j + 0];
        float dy = xi1 - x[3 * j + 1];
        float dz = xi2 - x[3 * j + 2];
        float d2 = dx * dx + dy * dy + dz * dz;
        float a = 0.0f, rr = 0.0f, inv = 0.0f;
        if (j != i) {
            float d = sqrtf(d2);
            if (d <= 6.0f) {
                float fc = 0.5f * (__cosf(0.52359877559829887f * d) + 1.0f);
                a = __expf(-0.5f * d2) * fc;
                float dm = d - 1.0f;  // RS = 1
                rr = __expf(-0.5f * dm * dm) * fc;
            }
            inv = rsqrtf(d2);
        }
        A[i * N + j] = a;
        racc += rr;
        val[r] = make_float4(dx * inv, dy * inv, dz * inv, a);
        keep[r] = (a > EPSA) ? 1 : 0;
    }

    // sorted compaction: chunk c = (j>>6) = w + 2r; ballot + prefix per chunk
    __shared__ int bcnt[6], bbase[6], realn;
    int pfx[3];
#pragma unroll
    for (int r = 0; r < 3; ++r) {
        unsigned long long m = __ballot(keep[r]);
        pfx[r] = __popcll(m & ((1ull << lane) - 1ull));
        if (lane == 0) bcnt[w + 2 * r] = __popcll(m);
    }
    __syncthreads();
    if (t == 0) {
        int s = 0;
#pragma unroll
        for (int c = 0; c < 6; ++c) { bbase[c] = s; s += bcnt[c]; }
        realn = s;
        cnt[i] = (s + 7) & ~7;   // padded count (multiple of 8)
        ang[i] = 0.0f;
        done[i] = 0;             // completion counter for ang's fused-MLP tail
    }
    __syncthreads();
#pragma unroll
    for (int r = 0; r < 3; ++r) {
        if (keep[r]) {
            const int slot = bbase[w + 2 * r] + pfx[r];
            nbr4[i * N + slot] = val[r];
            nbrJ[i * N + slot] = t + 128 * r;
        }
    }
    // zero-pad to multiple of 8 (self-masking entries)
    const int rn = realn;
    const int np = (rn + 7) & ~7;
    if (t < np - rn) {
        nbr4[i * N + rn + t] = make_float4(0.f, 0.f, 0.f, 0.f);
        nbrJ[i * N + rn + t] = i;
    }

    __shared__ float red[2];
    float v = wave_reduce(racc);
    if (lane == 0) red[w] = v;
    __syncthreads();
    if (t == 0) rad[i] = red[0] + red[1];
}

// ---------------- Kernel 2: angular TRIANGLE sum + fused MLP tail -------------
// grid (N, 2), 256 threads. One compact-k per thread; j batches of 8 with
// block-uniform addresses (s_load constant-cache path). TRIANGLE: pair (j,k)
// counted once via per-wave batch start (8*wave) + per-lane mask (s > ks);
// no 0.5 factor. Last-finisher block (done counter) computes both MLPs and
// writes out[i] -- removes the third kernel launch entirely.
__global__ __launch_bounds__(256) void ang_kernel(
    const float* __restrict__ A, const float4* __restrict__ nbr4,
    const int* __restrict__ nbrJ, const int* __restrict__ cnt,
    const float* __restrict__ rad, float* __restrict__ ang,
    int* __restrict__ done, float* __restrict__ out,
    const float* __restrict__ w1a, const float* __restrict__ b1a,
    const float* __restrict__ w2a, const float* __restrict__ b2a,
    const float* __restrict__ w3a, const float* __restrict__ b3a,
    const float* __restrict__ w1b, const float* __restrict__ b1b,
    const float* __restrict__ w2b, const float* __restrict__ b2b,
    const float* __restrict__ w3b, const float* __restrict__ b3b) {
    const int i = blockIdx.x;
    const int jc = blockIdx.y;          // 0..1: batch-strided j split
    const int t = threadIdx.x;
    const int n = cnt[i];               // multiple of 8
    const int iN = i * N;
    const int nb = n >> 3;              // number of 8-wide j batches

    float acc = 0.0f;
    for (int ks0 = 0; ks0 < n; ks0 += 256) {   // one iter unless n > 256
        const int ks = ks0 + t;
        const bool valid = ks < n;
        float4 K = valid ? nbr4[iN + ks] : make_float4(0.f, 0.f, 0.f, 0.f);
        const int kcol = valid ? nbrJ[iN + ks] : 0;
        const float kx = -0.8f * K.x, ky = -0.8f * K.y, kz = -0.8f * K.z;
        const float kA = K.w;
        const float* Acol = A + kcol;

        // triangle: wave w only needs batches covering slots >= its min ks.
        // base8 = (ks0 + 64w)/8 is even, so b == jc (mod 2) start is base8+jc.
        const int bw = ((ks0 >> 3) + ((t >> 6) << 3)) + jc;

        float cacc = 0.0f;
        for (int b = bw; b < nb; b += 2) {
            const int s0 = b << 3;
            float a8[8];
#pragma unroll
            for (int q = 0; q < 8; ++q)          // 8 gathers in flight
                a8[q] = Acol[nbrJ[iN + s0 + q] * N];
#pragma unroll
            for (int q = 0; q < 8; ++q) {
                float4 J = nbr4[iN + s0 + q];    // uniform -> s_load_dwordx4
                float bb = fmaf(J.x, kx, fmaf(J.y, ky, fmaf(J.z, kz, 1.0f)));
                float p = EXP2F(0.6f * LOG2F(bb));     // base^zeta
                float aw = (s0 + q > ks) ? a8[q] : 0.0f;  // strict upper triangle
                cacc = fmaf(J.w * aw, p, cacc);
            }
        }
        acc = fmaf(kA, cacc, acc);
    }

    __shared__ float red[4];
    __shared__ int s_win;
    __shared__ float s_ang;
    float v = wave_reduce(acc);
    if ((t & 63) == 0) red[t >> 6] = v;
    __syncthreads();
    if (t == 0) {
        float s = red[0] + red[1] + red[2] + red[3];
        atomicAdd(&ang[i], s);
        __threadfence();
        int old = atomicAdd(&done[i], 1);
        s_win = (old == 1);
        if (old == 1) s_ang = atomicAdd(&ang[i], 0.0f);  // coherent total read
    }
    __syncthreads();
    if (!s_win) return;                 // block-uniform -> barriers below legal

    // ---------------- fused MLP tail (winning block only) ----------------
    // G = [2^(1-zeta) * tri_sum, rad]; nets A/B on 40 threads each.
    __shared__ float h1s[2][40];
    __shared__ float contrib[80];
    const float g0 = 1.3195079107728942f * s_ang;   // 2^0.4 (triangle: no 0.5)
    const float g1 = rad[i];

    if (t < 80) {
        const int net = t / 40, u = t - net * 40;
        const float* w1 = net ? w1b : w1a;
        const float* b1 = net ? b1b : b1a;
        float z = fmaf(w1[2 * u], g0, fmaf(w1[2 * u + 1], g1, b1[u]));
        h1s[net][u] = 1.0f / fmaf(z, z, 1.0f);
    }
    __syncthreads();
    if (t < 80) {
        const int net = t / 40, vv = t - net * 40;
        const float* w2 = net ? w2b : w2a;
        const float* b2 = net ? b2b : b2a;
        const float* w3 = net ? w3b : w3a;
        const float* row = w2 + vv * 40;
        float z = b2[vv];
#pragma unroll 8
        for (int u = 0; u < 40; ++u) z = fmaf(row[u], h1s[net][u], z);
        float h = 1.0f / fmaf(z, z, 1.0f);
        contrib[t] = w3[vv] * h;
    }
    __syncthreads();
    if (t < 2) {
        const float* b3 = t ? b3b : b3a;
        float q = b3[0];
        for (int vv = 0; vv < 40; ++vv) q += contrib[t * 40 + vv];
        contrib[t] = q;                 // contrib[0]=q1(netA), contrib[1]=q2(netB)
    }
    __syncthreads();
    if (t == 0) out[i] = (i == 8) ? contrib[1] : contrib[0];
}

extern "C" void kernel_launch(void* const* d_in, const int* in_sizes, int n_in,
                              void* d_out, int out_size, void* d_ws, size_t ws_size,
                              hipStream_t stream) {
    const float* x = (const float*)d_in[0];
    const float* w1a = (const float*)d_in[1];
    const float* b1a = (const float*)d_in[2];
    const float* w2a = (const float*)d_in[3];
    const float* b2a = (const float*)d_in[4];
    const float* w3a = (const float*)d_in[5];
    const float* b3a = (const float*)d_in[6];
    const float* w1b = (const float*)d_in[7];
    const float* b1b = (const float*)d_in[8];
    const float* w2b = (const float*)d_in[9];
    const float* b2b = (const float*)d_in[10];
    const float* w3b = (const float*)d_in[11];
    const float* b3b = (const float*)d_in[12];
    float* out = (float*)d_out;

    // ws layout (float offsets): A[147456] | nbr4[4*147456] | nbrJ[147456] |
    //                            rad[384] | ang[384] | cnt[384] | done[384]
    float* ws = (float*)d_ws;
    float* A = ws;
    float4* nbr4 = (float4*)(ws + 147456);          // 16B-aligned
    int* nbrJ = (int*)(ws + 147456 + 4 * 147456);
    float* rad = ws + 147456 * 6;
    float* ang = rad + 384;
    int* cnt = (int*)(ang + 384);
    int* done = cnt + 384;

    hipLaunchKernelGGL(pair_kernel, dim3(N), dim3(128), 0, stream,
                       x, A, nbr4, nbrJ, cnt, rad, ang, done);
    hipLaunchKernelGGL(ang_kernel, dim3(N, 2), dim3(256), 0, stream,
                       A, nbr4, nbrJ, cnt, rad, ang, done, out,
                       w1a, b1a, w2a, b2a, w3a, b3a,
                       w1b, b1b, w2b, b2b, w3b, b3b);
}